// Round 16
// baseline (1734.936 us; speedup 1.0000x reference)
//
#include <hip/hip_runtime.h>

typedef __attribute__((ext_vector_type(4))) float f32x4;
typedef __attribute__((ext_vector_type(2))) float f32x2;

#define RD 256
#define NLAGS 512
#define NPAST 128

__device__ __forceinline__ float ftanh(float x) {
    float ax = __builtin_fabsf(x);
    float e = __builtin_amdgcn_exp2f(ax * 2.8853900817779268f);   // 2*log2(e)
    float r = 1.0f - 2.0f * __builtin_amdgcn_rcpf(e + 1.0f);
    return __builtin_copysignf(r, x);
}

__device__ __forceinline__ unsigned pkh(_Float16 lo, _Float16 hi) {
    unsigned a = (unsigned)__builtin_bit_cast(unsigned short, lo);
    unsigned b = (unsigned)__builtin_bit_cast(unsigned short, hi);
    return a | (b << 16);
}

// DPP quad-perm butterfly add (pure VALU): xor1 = 0xB1, xor2 = 0x4E
#define DPPADD(v, ctrl) { int _t = __builtin_amdgcn_update_dpp(0, __float_as_int(v), ctrl, 0xf, 0xf, true); \
                          (v) += __int_as_float(_t); }
#define QUADSUM(v) DPPADD(v, 0xB1) DPPADD(v, 0x4E)

#define RPT16(M) M(0) M(1) M(2) M(3) M(4) M(5) M(6) M(7) M(8) M(9) M(10) M(11) M(12) M(13) M(14) M(15)
#define RPTP(M) M(0,0,1) M(1,2,3) M(2,4,5) M(3,6,7) M(4,8,9) M(5,10,11) M(6,12,13) M(7,14,15)

// Per-thread weights, 2 rows x 64 cols:
//   B1 f32 -> 128 scalars HOMED IN AGPRs ("+a" one-time pin). Consumed via an
//     explicit v_accvgpr_read + v_fma_f32 -> exactly 1 copy + 1 FMA per MAC,
//     the architectural minimum for AGPR-resident data (VALU can't read AGPRs
//     directly on gfx950, proven r11). Frees the 128-slot arch file for:
//   B2 hi  -> 64 packed-f16 arch VGPRs ("+v" pin), zero-copy MIX operands.
//   B2 lo  -> fp8 x4096 residual in LDS, decoded + v_pk_fma_f32.
#define DECL_W(c) \
    float w##c##_0, w##c##_1, w##c##_2, w##c##_3, w##c##_4, w##c##_5, w##c##_6, w##c##_7; \
    unsigned hA_##c, hB_##c, hC_##c, hD_##c; \
    unsigned lwA_##c, lwB_##c;

#define STG(c) { \
    int off = (((c) << 4) + q64) & 0xF0; \
    f32x4 a0 = *(const f32x4*)(pB1 + off); \
    f32x4 a1 = *(const f32x4*)(pB1 + 1024 + off); \
    w##c##_0 = a0[0]*sc1; w##c##_1 = a0[1]*sc1; w##c##_2 = a0[2]*sc1; w##c##_3 = a0[3]*sc1; \
    w##c##_4 = a1[0]*sc1; w##c##_5 = a1[1]*sc1; w##c##_6 = a1[2]*sc1; w##c##_7 = a1[3]*sc1; \
    f32x4 e0 = *(const f32x4*)(pB2 + off) * sc2; \
    f32x4 e1 = *(const f32x4*)(pB2 + 1024 + off) * sc2; \
    _Float16 h0=(_Float16)e0[0], h1=(_Float16)e0[1], h2=(_Float16)e0[2], h3=(_Float16)e0[3]; \
    _Float16 h4=(_Float16)e1[0], h5=(_Float16)e1[1], h6=(_Float16)e1[2], h7=(_Float16)e1[3]; \
    hA_##c = pkh(h0,h1); hB_##c = pkh(h2,h3); hC_##c = pkh(h4,h5); hD_##c = pkh(h6,h7); \
    float l0=(e0[0]-(float)h0)*4096.f, l1=(e0[1]-(float)h1)*4096.f; \
    float l2=(e0[2]-(float)h2)*4096.f, l3=(e0[3]-(float)h3)*4096.f; \
    float m0=(e1[0]-(float)h4)*4096.f, m1=(e1[1]-(float)h5)*4096.f; \
    float m2=(e1[2]-(float)h6)*4096.f, m3=(e1[3]-(float)h7)*4096.f; \
    unsigned uA = (unsigned)__builtin_amdgcn_cvt_pk_fp8_f32(l0, l1, 0, false); \
    uA = (unsigned)__builtin_amdgcn_cvt_pk_fp8_f32(l2, l3, (int)uA, true); \
    unsigned uB = (unsigned)__builtin_amdgcn_cvt_pk_fp8_f32(m0, m1, 0, false); \
    uB = (unsigned)__builtin_amdgcn_cvt_pk_fp8_f32(m2, m3, (int)uB, true); \
    lwA_##c = uA; lwB_##c = uB; }

// one-time class-steering pins after staging:
//   B1 -> AGPR home (frees the arch file), B2hi -> arch home (zero-copy MIX)
#define KEEPW(c) \
    asm volatile("" : "+a"(w##c##_0), "+a"(w##c##_1), "+a"(w##c##_2), "+a"(w##c##_3), \
                      "+a"(w##c##_4), "+a"(w##c##_5), "+a"(w##c##_6), "+a"(w##c##_7)); \
    asm volatile("" : "+v"(hA_##c), "+v"(hB_##c), "+v"(hC_##c), "+v"(hD_##c));

#define STO(p, c0, c1) lo_lds[((p) << 9) + tid] = make_uint4(lwA_##c0, lwB_##c0, lwA_##c1, lwB_##c1);

// explicit minimal AGPR consumption: read + scalar FMA (2 instr / MAC)
#define B1FMA(acc, w, r) { float t_; \
    asm("v_accvgpr_read_b32 %0, %1" : "=v"(t_) : "a"(w)); \
    acc = __builtin_fmaf(t_, r, acc); }

// packed dual-f32 FMA: 2 MACs / instruction
#define PKFMA(acc, w, r) asm("v_pk_fma_f32 %0, %1, %2, %0" : "+v"(acc) : "v"(w), "v"(r));
// packed-f16 x f32 mixed FMA (1 op/MAC, no cvt)
#define MIXLO(acc, u, r) asm("v_fma_mix_f32 %0, %1, %2, %0 op_sel_hi:[1,0,0]" : "+v"(acc) : "v"(u), "v"(r));
#define MIXHI(acc, u, r) asm("v_fma_mix_f32 %0, %1, %2, %0 op_sel:[1,0,0] op_sel_hi:[1,0,0]" : "+v"(acc) : "v"(u), "v"(r));

// fp8-lo: decode pair-wise then packed FMA (6 instr / 8 MACs)
#define F4L(accv, w, rv01, rv23) { \
    f32x2 pA_ = __builtin_amdgcn_cvt_pk_f32_fp8((int)(w), false); \
    f32x2 pB_ = __builtin_amdgcn_cvt_pk_f32_fp8((int)(w), true); \
    PKFMA(accv, pA_, rv01) \
    PKFMA(accv, pB_, rv23) }

#define DOT1(c, wA, wB) { \
    f32x4 rv = *(const f32x4*)(RqR + ((((c) << 4) + q64) & 0xF0)); \
    f32x2 rv01 = f32x2{rv[0], rv[1]}; \
    f32x2 rv23 = f32x2{rv[2], rv[3]}; \
    B1FMA(acc1_0, w##c##_0, rv[0]) B1FMA(acc1_0, w##c##_1, rv[1]) \
    B1FMA(acc1_0, w##c##_2, rv[2]) B1FMA(acc1_0, w##c##_3, rv[3]) \
    B1FMA(acc1_1, w##c##_4, rv[0]) B1FMA(acc1_1, w##c##_5, rv[1]) \
    B1FMA(acc1_1, w##c##_6, rv[2]) B1FMA(acc1_1, w##c##_7, rv[3]) \
    MIXLO(acc2_0, hA_##c, rv[0]) MIXHI(acc2_0, hA_##c, rv[1]) \
    MIXLO(acc2_0, hB_##c, rv[2]) MIXHI(acc2_0, hB_##c, rv[3]) \
    MIXLO(acc2_1, hC_##c, rv[0]) MIXHI(acc2_1, hC_##c, rv[1]) \
    MIXLO(acc2_1, hD_##c, rv[2]) MIXHI(acc2_1, hD_##c, rv[3]) \
    F4L(accl_0v, wA, rv01, rv23) F4L(accl_1v, wB, rv01, rv23) }

#define DOTP(p, c0, c1) { \
    uint4 Lq = lo_lds[((p) << 9) + tid]; \
    const unsigned* Lw = (const unsigned*)&Lq; \
    DOT1(c0, Lw[0], Lw[1]) \
    DOT1(c1, Lw[2], Lw[3]) }

#define SCLF (1.0f / 4096.0f)

// ---------------------------------------------------------------------------
// Main SDE scan: one block (512 thr) per batch row.
// thread = (row-pair g = tid>>2, K-slice q = tid&3 of 64 cols)
// ---------------------------------------------------------------------------
__global__ __attribute__((amdgpu_num_vgpr(256), amdgpu_waves_per_eu(2, 2)))
void __launch_bounds__(512) sde_main_kernel(
    const float* __restrict__ inc, const float* __restrict__ Vn,
    const float* __restrict__ W1h, const float* __restrict__ b1h,
    const float* __restrict__ W1o, const float* __restrict__ b1o,
    const float* __restrict__ rho1p, const float* __restrict__ rho2p,
    const float* __restrict__ rho3p, const float* __restrict__ rho4p,
    const float* __restrict__ B1, const float* __restrict__ B2,
    const float* __restrict__ lam1, const float* __restrict__ lam2,
    const float* __restrict__ Wr, const float* __restrict__ brp,
    const float* __restrict__ rsig, float* __restrict__ out)
{
    const int tid  = threadIdx.x;
    const int b    = blockIdx.x;
    const int q    = tid & 3;           // K-slice (64 cols)
    const int g    = tid >> 2;          // row-pair 0..127
    const int lane = tid & 63;
    const int wvi  = tid >> 6;
    const int q64  = q << 6;
    const int myrow = 2 * g + (q & 1);

    __shared__ __align__(16) uint4 lo_lds[8 * 512];       // 64 KB fp8 residuals
    __shared__ __align__(16) float Rs[2][RD];
    __shared__ __align__(16) float inc_lds[NLAGS];
    __shared__ float red[2][8];
    __shared__ float hv[32];

    const float rho1 = *rho1p, rho2 = *rho2p, rho3 = *rho3p, rho4 = *rho4p;

    RPT16(DECL_W)
    {
        const float sc1 = rho1, sc2 = rho3;
        const char* pB1 = (const char*)(B1 + (2 * g) * RD) + (q << 8);
        const char* pB2 = (const char*)(B2 + (2 * g) * RD) + (q << 8);
        RPT16(STG)
        RPTP(STO)
    }
    RPT16(KEEPW)

    const float c1m  = rho2 * lam1[myrow];
    const float c2m  = rho4 * lam2[myrow];
    const float wrim = Wr[myrow];
    const float brv  = *brp;

    // prologue: increments, initial condition R0 = [rsig ; V]
    inc_lds[tid] = inc[b * NLAGS + tid];
    if (tid < 32) {
        float a = b1h[tid];
        const float* wrow = W1h + tid * 32;
        const float* vn = Vn + b * 32;
        for (int k = 0; k < 32; ++k) a = __builtin_fmaf(wrow[k], vn[k], a);
        hv[tid] = ftanh(a);
    }
    if (tid < RD - 30) ((float*)Rs)[tid] = rsig[tid];
    __syncthreads();
    if (tid == 0) inc_lds[1] = inc_lds[0] + inc_lds[1];   // dW[0] = inc0 + inc1
    if (tid < 30) {
        float a = b1o[tid];
        const float* wrow = W1o + tid * 32;
        for (int k = 0; k < 32; ++k) a = __builtin_fmaf(wrow[k], hv[k], a);
        ((float*)Rs)[(RD - 30) + tid] = a;
    }
    __syncthreads();

    float rmine = ((const float*)Rs)[myrow];

    // peeled readout of R0 -> out[b,0]
    {
        float p = (q < 2) ? rmine * wrim : 0.0f;
        QUADSUM(p)
        p += __shfl_xor(p, 4, 64);
        p += __shfl_xor(p, 8, 64);
        p += __shfl_xor(p, 16, 64);
        p += __shfl_xor(p, 32, 64);
        if (lane == 0) red[0][wvi] = p;
    }
    __syncthreads();
    if (wvi == 0) {
        float s = (lane < 8) ? red[0][lane] : 0.0f;
        s += __shfl_xor(s, 1, 64);
        s += __shfl_xor(s, 2, 64);
        s += __shfl_xor(s, 4, 64);
        if (lane == 0) out[(size_t)b * NLAGS] = s + brv;
    }

    char* RsB = (char*)Rs;
    int rbase = 0;
    float* outp = out + (size_t)b * NLAGS;

#pragma unroll 1
    for (int t = 0; t < NLAGS - 1; ++t) {
        const float dwt = inc_lds[t + 1];
        const char* RqR = RsB + rbase + (q << 8);
        float acc1_0 = 0.f, acc1_1 = 0.f;
        f32x2 accl_0v = f32x2{0.f, 0.f}, accl_1v = f32x2{0.f, 0.f};
        float acc2_0 = 0.f, acc2_1 = 0.f;
        RPTP(DOTP)
        float a1_0 = acc1_0;
        float a1_1 = acc1_1;
        float a2_0 = __builtin_fmaf(accl_0v[0] + accl_0v[1], SCLF, acc2_0);
        float a2_1 = __builtin_fmaf(accl_1v[0] + accl_1v[1], SCLF, acc2_1);
        QUADSUM(a1_0) QUADSUM(a1_1) QUADSUM(a2_0) QUADSUM(a2_1)
        float s1 = (q & 1) ? a1_1 : a1_0;
        float s2 = (q & 1) ? a2_1 : a2_0;
        float rn = rmine + ftanh(s1 + c1m) + ftanh(s2 + c2m) * dwt;
        rmine = rn;
        if (q < 2) *(float*)(RsB + (rbase ^ 1024) + myrow * 4) = rn;
        float p = (q < 2) ? rn * wrim : 0.0f;
        QUADSUM(p)
        p += __shfl_xor(p, 4, 64);
        p += __shfl_xor(p, 8, 64);
        p += __shfl_xor(p, 16, 64);
        p += __shfl_xor(p, 32, 64);
        const int slot = (t + 1) & 1;
        if (lane == 0) red[slot][wvi] = p;
        __syncthreads();
        if (wvi == 0) {
            float s = (lane < 8) ? red[slot][lane] : 0.0f;
            s += __shfl_xor(s, 1, 64);
            s += __shfl_xor(s, 2, 64);
            s += __shfl_xor(s, 4, 64);
            if (lane == 0) outp[t + 1] = s + brv;
        }
        rbase ^= 1024;
    }
}

// ---------------------------------------------------------------------------
// rsig scan (batch-independent), one block; same structure on A1/A2.
// ---------------------------------------------------------------------------
__global__ __attribute__((amdgpu_num_vgpr(256), amdgpu_waves_per_eu(2, 2)))
void __launch_bounds__(512) rsig_kernel(
    const float* __restrict__ xp,
    const float* __restrict__ A1, const float* __restrict__ A2,
    const float* __restrict__ xi1, const float* __restrict__ xi2,
    const float* __restrict__ W2h, const float* __restrict__ b2h,
    const float* __restrict__ W2o, const float* __restrict__ b2o,
    float* __restrict__ rsig_out)
{
    const int tid = threadIdx.x;
    const int q   = tid & 3;
    const int g   = tid >> 2;
    const int q64 = q << 6;
    const int myrow = 2 * g + (q & 1);

    __shared__ __align__(16) uint4 lo_lds[8 * 512];       // 64 KB
    __shared__ __align__(16) float Rs[2][RD];
    __shared__ float dx_lds[NPAST];
    __shared__ float Zlin[RD];
    __shared__ float hh[32];

    RPT16(DECL_W)
    {
        const float sc1 = 1.0f, sc2 = 1.0f;
        const char* pB1 = (const char*)(A1 + (2 * g) * RD) + (q << 8);
        const char* pB2 = (const char*)(A2 + (2 * g) * RD) + (q << 8);
        RPT16(STG)
        RPTP(STO)
    }
    RPT16(KEEPW)

    const float x1m = xi1[myrow];
    const float x2m = xi2[myrow];

    if (tid < NPAST - 1) dx_lds[tid] = xp[tid + 1] - xp[tid];
    ((float*)Rs)[tid] = 0.0f;           // zero both buffers (512 floats)
    __syncthreads();

    float zmine = 0.0f;
    char* RsB = (char*)Rs;
    int rbase = 0;

#pragma unroll 1
    for (int t = 0; t < NPAST - 1; ++t) {
        const float dxt = dx_lds[t];
        const char* RqR = RsB + rbase + (q << 8);
        float acc1_0 = 0.f, acc1_1 = 0.f;
        f32x2 accl_0v = f32x2{0.f, 0.f}, accl_1v = f32x2{0.f, 0.f};
        float acc2_0 = 0.f, acc2_1 = 0.f;
        RPTP(DOTP)
        float a1_0 = acc1_0;
        float a1_1 = acc1_1;
        float a2_0 = __builtin_fmaf(accl_0v[0] + accl_0v[1], SCLF, acc2_0);
        float a2_1 = __builtin_fmaf(accl_1v[0] + accl_1v[1], SCLF, acc2_1);
        QUADSUM(a1_0) QUADSUM(a1_1) QUADSUM(a2_0) QUADSUM(a2_1)
        float s1 = (q & 1) ? a1_1 : a1_0;
        float s2 = (q & 1) ? a2_1 : a2_0;
        zmine = zmine + ftanh(s1 + x1m) + ftanh(s2 + x2m) * dxt;
        if (q < 2) *(float*)(RsB + (rbase ^ 1024) + myrow * 4) = zmine;
        __syncthreads();
        rbase ^= 1024;
    }

    if (q < 2) Zlin[myrow] = zmine;
    __syncthreads();

    if (tid < 32) {
        float a = b2h[tid];
        const float* wrow = W2h + tid * RD;
        for (int k = 0; k < RD; ++k) a = __builtin_fmaf(wrow[k], Zlin[k], a);
        hh[tid] = ftanh(a);
    }
    __syncthreads();
    if (tid < RD - 30) {
        float a = b2o[tid];
        const float* wrow = W2o + tid * 32;
        for (int k = 0; k < 32; ++k) a = __builtin_fmaf(wrow[k], hh[k], a);
        rsig_out[tid] = a;
    }
}

extern "C" void kernel_launch(void* const* d_in, const int* in_sizes, int n_in,
                              void* d_out, int out_size, void* d_ws, size_t ws_size,
                              hipStream_t stream) {
    const float* x_past  = (const float*)d_in[2];
    const float* V_noise = (const float*)d_in[3];
    const float* inc     = (const float*)d_in[4];
    const float* W1h     = (const float*)d_in[5];
    const float* b1h     = (const float*)d_in[6];
    const float* W1o     = (const float*)d_in[7];
    const float* b1o     = (const float*)d_in[8];
    const float* W2h     = (const float*)d_in[9];
    const float* b2h     = (const float*)d_in[10];
    const float* W2o     = (const float*)d_in[11];
    const float* b2o     = (const float*)d_in[12];
    const float* rho1    = (const float*)d_in[13];
    const float* rho2    = (const float*)d_in[14];
    const float* rho3    = (const float*)d_in[15];
    const float* rho4    = (const float*)d_in[16];
    const float* B1      = (const float*)d_in[17];
    const float* B2      = (const float*)d_in[18];
    const float* lam1    = (const float*)d_in[19];
    const float* lam2    = (const float*)d_in[20];
    const float* A1      = (const float*)d_in[21];
    const float* A2      = (const float*)d_in[22];
    const float* xi1     = (const float*)d_in[23];
    const float* xi2     = (const float*)d_in[24];
    const float* Wr      = (const float*)d_in[25];
    const float* br      = (const float*)d_in[26];

    float* rsig_ws = (float*)d_ws;   // 226 floats

    rsig_kernel<<<1, 512, 0, stream>>>(x_past, A1, A2, xi1, xi2,
                                       W2h, b2h, W2o, b2o, rsig_ws);

    sde_main_kernel<<<256, 512, 0, stream>>>(inc, V_noise, W1h, b1h, W1o, b1o,
                                             rho1, rho2, rho3, rho4,
                                             B1, B2, lam1, lam2, Wr, br,
                                             rsig_ws, (float*)d_out);
}

// Round 17
// 1152.537 us; speedup vs baseline: 1.5053x; 1.5053x over previous
//
#include <hip/hip_runtime.h>

typedef __attribute__((ext_vector_type(4))) float f32x4;
typedef __attribute__((ext_vector_type(2))) float f32x2;

#define RD 256
#define NLAGS 512
#define NPAST 128

__device__ __forceinline__ float ftanh(float x) {
    float ax = __builtin_fabsf(x);
    float e = __builtin_amdgcn_exp2f(ax * 2.8853900817779268f);   // 2*log2(e)
    float r = 1.0f - 2.0f * __builtin_amdgcn_rcpf(e + 1.0f);
    return __builtin_copysignf(r, x);
}

__device__ __forceinline__ unsigned pkh(_Float16 lo, _Float16 hi) {
    unsigned a = (unsigned)__builtin_bit_cast(unsigned short, lo);
    unsigned b = (unsigned)__builtin_bit_cast(unsigned short, hi);
    return a | (b << 16);
}

// DPP add helper (old=0, full masks, bound_ctrl): v += dpp_move(v, ctrl)
#define DPPADD(v, ctrl) { int _t = __builtin_amdgcn_update_dpp(0, __float_as_int(v), ctrl, 0xf, 0xf, true); \
                          (v) += __int_as_float(_t); }
// quad reduce (K-slices): xor1=0xB1, xor2=0x4E
#define QUADSUM(v) DPPADD(v, 0xB1) DPPADD(v, 0x4E)
// canonical wave64 sum, pure VALU, result in lane 63:
// row_shr:1/2/4/8 then row_bcast:15 (0x142), row_bcast:31 (0x143)
#define WSUM(v) DPPADD(v, 0x111) DPPADD(v, 0x112) DPPADD(v, 0x114) DPPADD(v, 0x118) \
                DPPADD(v, 0x142) DPPADD(v, 0x143)

#define RPT16(M) M(0) M(1) M(2) M(3) M(4) M(5) M(6) M(7) M(8) M(9) M(10) M(11) M(12) M(13) M(14) M(15)
#define RPTP(M) M(0,0,1) M(1,2,3) M(2,4,5) M(3,6,7) M(4,8,9) M(5,10,11) M(6,12,13) M(7,14,15)

// Per-thread weights, 2 rows x 64 cols (r14 configuration — best measured):
//   B1 f32 -> 64 f32x2 pairs (v_pk_fma_f32)
//   B2 hi  -> 64 packed-f16 VGPRs (v_fma_mix_f32)
//   B2 lo  -> fp8 x4096 residual in LDS, decoded + v_pk_fma_f32
#define DECL_W(c) \
    f32x2 w##c##_01, w##c##_23, w##c##_45, w##c##_67; \
    unsigned hA_##c, hB_##c, hC_##c, hD_##c; \
    unsigned lwA_##c, lwB_##c;

#define STG(c) { \
    int off = (((c) << 4) + q64) & 0xF0; \
    f32x4 a0 = *(const f32x4*)(pB1 + off); \
    f32x4 a1 = *(const f32x4*)(pB1 + 1024 + off); \
    w##c##_01 = f32x2{a0[0]*sc1, a0[1]*sc1}; \
    w##c##_23 = f32x2{a0[2]*sc1, a0[3]*sc1}; \
    w##c##_45 = f32x2{a1[0]*sc1, a1[1]*sc1}; \
    w##c##_67 = f32x2{a1[2]*sc1, a1[3]*sc1}; \
    f32x4 e0 = *(const f32x4*)(pB2 + off) * sc2; \
    f32x4 e1 = *(const f32x4*)(pB2 + 1024 + off) * sc2; \
    _Float16 h0=(_Float16)e0[0], h1=(_Float16)e0[1], h2=(_Float16)e0[2], h3=(_Float16)e0[3]; \
    _Float16 h4=(_Float16)e1[0], h5=(_Float16)e1[1], h6=(_Float16)e1[2], h7=(_Float16)e1[3]; \
    hA_##c = pkh(h0,h1); hB_##c = pkh(h2,h3); hC_##c = pkh(h4,h5); hD_##c = pkh(h6,h7); \
    float l0=(e0[0]-(float)h0)*4096.f, l1=(e0[1]-(float)h1)*4096.f; \
    float l2=(e0[2]-(float)h2)*4096.f, l3=(e0[3]-(float)h3)*4096.f; \
    float m0=(e1[0]-(float)h4)*4096.f, m1=(e1[1]-(float)h5)*4096.f; \
    float m2=(e1[2]-(float)h6)*4096.f, m3=(e1[3]-(float)h7)*4096.f; \
    unsigned uA = (unsigned)__builtin_amdgcn_cvt_pk_fp8_f32(l0, l1, 0, false); \
    uA = (unsigned)__builtin_amdgcn_cvt_pk_fp8_f32(l2, l3, (int)uA, true); \
    unsigned uB = (unsigned)__builtin_amdgcn_cvt_pk_fp8_f32(m0, m1, 0, false); \
    uB = (unsigned)__builtin_amdgcn_cvt_pk_fp8_f32(m2, m3, (int)uB, true); \
    lwA_##c = uA; lwB_##c = uB; }

// one-time opaque pin after staging (anti-remat anchor; r14's setting)
#define KEEPW(c) asm volatile("" : \
    "+v"(w##c##_01), "+v"(w##c##_23), "+v"(w##c##_45), "+v"(w##c##_67), \
    "+v"(hA_##c), "+v"(hB_##c), "+v"(hC_##c), "+v"(hD_##c));

#define STO(p, c0, c1) lo_lds[((p) << 9) + tid] = make_uint4(lwA_##c0, lwB_##c0, lwA_##c1, lwB_##c1);

// packed dual-f32 FMA: 2 MACs / instruction
#define PKFMA(acc, w, r) asm("v_pk_fma_f32 %0, %1, %2, %0" : "+v"(acc) : "v"(w), "v"(r));
// packed-f16 x f32 mixed FMA (1 op/MAC, no cvt)
#define MIXLO(acc, u, r) asm("v_fma_mix_f32 %0, %1, %2, %0 op_sel_hi:[1,0,0]" : "+v"(acc) : "v"(u), "v"(r));
#define MIXHI(acc, u, r) asm("v_fma_mix_f32 %0, %1, %2, %0 op_sel:[1,0,0] op_sel_hi:[1,0,0]" : "+v"(acc) : "v"(u), "v"(r));

// fp8-lo: decode pair-wise then packed FMA (6 instr / 8 MACs)
#define F4L(accv, w, rv01, rv23) { \
    f32x2 pA_ = __builtin_amdgcn_cvt_pk_f32_fp8((int)(w), false); \
    f32x2 pB_ = __builtin_amdgcn_cvt_pk_f32_fp8((int)(w), true); \
    PKFMA(accv, pA_, rv01) \
    PKFMA(accv, pB_, rv23) }

#define DOT1(c, wA, wB) { \
    f32x4 rv = *(const f32x4*)(RqR + ((((c) << 4) + q64) & 0xF0)); \
    f32x2 rv01 = f32x2{rv[0], rv[1]}; \
    f32x2 rv23 = f32x2{rv[2], rv[3]}; \
    PKFMA(acc1_0v, w##c##_01, rv01) PKFMA(acc1_0v, w##c##_23, rv23) \
    PKFMA(acc1_1v, w##c##_45, rv01) PKFMA(acc1_1v, w##c##_67, rv23) \
    MIXLO(acc2_0, hA_##c, rv[0]) MIXHI(acc2_0, hA_##c, rv[1]) \
    MIXLO(acc2_0, hB_##c, rv[2]) MIXHI(acc2_0, hB_##c, rv[3]) \
    MIXLO(acc2_1, hC_##c, rv[0]) MIXHI(acc2_1, hC_##c, rv[1]) \
    MIXLO(acc2_1, hD_##c, rv[2]) MIXHI(acc2_1, hD_##c, rv[3]) \
    F4L(accl_0v, wA, rv01, rv23) F4L(accl_1v, wB, rv01, rv23) }

#define DOTP(p, c0, c1) { \
    uint4 Lq = lo_lds[((p) << 9) + tid]; \
    const unsigned* Lw = (const unsigned*)&Lq; \
    DOT1(c0, Lw[0], Lw[1]) \
    DOT1(c1, Lw[2], Lw[3]) }

#define SCLF (1.0f / 4096.0f)

// ---------------------------------------------------------------------------
// Main SDE scan: one block (512 thr) per batch row.
// thread = (row-pair g = tid>>2, K-slice q = tid&3 of 64 cols)
// ---------------------------------------------------------------------------
__global__ __attribute__((amdgpu_num_vgpr(256), amdgpu_waves_per_eu(2, 2)))
void __launch_bounds__(512) sde_main_kernel(
    const float* __restrict__ inc, const float* __restrict__ Vn,
    const float* __restrict__ W1h, const float* __restrict__ b1h,
    const float* __restrict__ W1o, const float* __restrict__ b1o,
    const float* __restrict__ rho1p, const float* __restrict__ rho2p,
    const float* __restrict__ rho3p, const float* __restrict__ rho4p,
    const float* __restrict__ B1, const float* __restrict__ B2,
    const float* __restrict__ lam1, const float* __restrict__ lam2,
    const float* __restrict__ Wr, const float* __restrict__ brp,
    const float* __restrict__ rsig, float* __restrict__ out)
{
    const int tid  = threadIdx.x;
    const int b    = blockIdx.x;
    const int q    = tid & 3;           // K-slice (64 cols)
    const int g    = tid >> 2;          // row-pair 0..127
    const int lane = tid & 63;
    const int wvi  = tid >> 6;
    const int q64  = q << 6;
    const int myrow = 2 * g + (q & 1);

    __shared__ __align__(16) uint4 lo_lds[8 * 512];       // 64 KB fp8 residuals
    __shared__ __align__(16) float Rs[2][RD];
    __shared__ __align__(16) float inc_lds[NLAGS];
    __shared__ __align__(16) float red[NLAGS][8];         // 16 KB per-step wave partials
    __shared__ float hv[32];

    const float rho1 = *rho1p, rho2 = *rho2p, rho3 = *rho3p, rho4 = *rho4p;

    RPT16(DECL_W)
    {
        const float sc1 = rho1, sc2 = rho3;
        const char* pB1 = (const char*)(B1 + (2 * g) * RD) + (q << 8);
        const char* pB2 = (const char*)(B2 + (2 * g) * RD) + (q << 8);
        RPT16(STG)
        RPTP(STO)
    }
    RPT16(KEEPW)

    const float c1m  = rho2 * lam1[myrow];
    const float c2m  = rho4 * lam2[myrow];
    const float wrim = Wr[myrow];
    const float brv  = *brp;

    // prologue: increments, initial condition R0 = [rsig ; V]
    inc_lds[tid] = inc[b * NLAGS + tid];
    if (tid < 32) {
        float a = b1h[tid];
        const float* wrow = W1h + tid * 32;
        const float* vn = Vn + b * 32;
        for (int k = 0; k < 32; ++k) a = __builtin_fmaf(wrow[k], vn[k], a);
        hv[tid] = ftanh(a);
    }
    if (tid < RD - 30) ((float*)Rs)[tid] = rsig[tid];
    __syncthreads();
    if (tid == 0) inc_lds[1] = inc_lds[0] + inc_lds[1];   // dW[0] = inc0 + inc1
    if (tid < 30) {
        float a = b1o[tid];
        const float* wrow = W1o + tid * 32;
        for (int k = 0; k < 32; ++k) a = __builtin_fmaf(wrow[k], hv[k], a);
        ((float*)Rs)[(RD - 30) + tid] = a;
    }
    __syncthreads();

    float rmine = ((const float*)Rs)[myrow];

    // peeled readout of R0 -> red[0][*] (summed in final pass)
    {
        float p = (q < 2) ? rmine * wrim : 0.0f;
        WSUM(p)
        if (lane == 63) red[0][wvi] = p;
    }

    char* RsB = (char*)Rs;
    int rbase = 0;
    float* outp = out + (size_t)b * NLAGS;

#pragma unroll 1
    for (int t = 0; t < NLAGS - 1; ++t) {
        const float dwt = inc_lds[t + 1];
        const char* RqR = RsB + rbase + (q << 8);
        f32x2 acc1_0v = f32x2{0.f, 0.f}, acc1_1v = f32x2{0.f, 0.f};
        f32x2 accl_0v = f32x2{0.f, 0.f}, accl_1v = f32x2{0.f, 0.f};
        float acc2_0 = 0.f, acc2_1 = 0.f;
        RPTP(DOTP)
        float a1_0 = acc1_0v[0] + acc1_0v[1];
        float a1_1 = acc1_1v[0] + acc1_1v[1];
        float a2_0 = __builtin_fmaf(accl_0v[0] + accl_0v[1], SCLF, acc2_0);
        float a2_1 = __builtin_fmaf(accl_1v[0] + accl_1v[1], SCLF, acc2_1);
        QUADSUM(a1_0) QUADSUM(a1_1) QUADSUM(a2_0) QUADSUM(a2_1)
        float s1 = (q & 1) ? a1_1 : a1_0;
        float s2 = (q & 1) ? a2_1 : a2_0;
        float rn = rmine + ftanh(s1 + c1m) + ftanh(s2 + c2m) * dwt;
        rmine = rn;
        if (q < 2) *(float*)(RsB + (rbase ^ 1024) + myrow * 4) = rn;
        __syncthreads();
        // output reduce AFTER the barrier: register-only inputs, overlaps the
        // next step's MAC issue; partials summed once in the final pass.
        float p = (q < 2) ? rn * wrim : 0.0f;
        WSUM(p)
        if (lane == 63) red[t + 1][wvi] = p;
        rbase ^= 1024;
    }
    __syncthreads();

    // final pass: out[b, t] = sum_w red[t][w] + br, one thread per lag
    {
        float s = brv;
        const float* rr = red[tid];
#pragma unroll
        for (int k = 0; k < 8; ++k) s += rr[k];
        outp[tid] = s;
    }
}

// ---------------------------------------------------------------------------
// rsig scan (batch-independent), one block; same structure on A1/A2.
// ---------------------------------------------------------------------------
__global__ __attribute__((amdgpu_num_vgpr(256), amdgpu_waves_per_eu(2, 2)))
void __launch_bounds__(512) rsig_kernel(
    const float* __restrict__ xp,
    const float* __restrict__ A1, const float* __restrict__ A2,
    const float* __restrict__ xi1, const float* __restrict__ xi2,
    const float* __restrict__ W2h, const float* __restrict__ b2h,
    const float* __restrict__ W2o, const float* __restrict__ b2o,
    float* __restrict__ rsig_out)
{
    const int tid = threadIdx.x;
    const int q   = tid & 3;
    const int g   = tid >> 2;
    const int q64 = q << 6;
    const int myrow = 2 * g + (q & 1);

    __shared__ __align__(16) uint4 lo_lds[8 * 512];       // 64 KB
    __shared__ __align__(16) float Rs[2][RD];
    __shared__ float dx_lds[NPAST];
    __shared__ float Zlin[RD];
    __shared__ float hh[32];

    RPT16(DECL_W)
    {
        const float sc1 = 1.0f, sc2 = 1.0f;
        const char* pB1 = (const char*)(A1 + (2 * g) * RD) + (q << 8);
        const char* pB2 = (const char*)(A2 + (2 * g) * RD) + (q << 8);
        RPT16(STG)
        RPTP(STO)
    }
    RPT16(KEEPW)

    const float x1m = xi1[myrow];
    const float x2m = xi2[myrow];

    if (tid < NPAST - 1) dx_lds[tid] = xp[tid + 1] - xp[tid];
    ((float*)Rs)[tid] = 0.0f;           // zero both buffers (512 floats)
    __syncthreads();

    float zmine = 0.0f;
    char* RsB = (char*)Rs;
    int rbase = 0;

#pragma unroll 1
    for (int t = 0; t < NPAST - 1; ++t) {
        const float dxt = dx_lds[t];
        const char* RqR = RsB + rbase + (q << 8);
        f32x2 acc1_0v = f32x2{0.f, 0.f}, acc1_1v = f32x2{0.f, 0.f};
        f32x2 accl_0v = f32x2{0.f, 0.f}, accl_1v = f32x2{0.f, 0.f};
        float acc2_0 = 0.f, acc2_1 = 0.f;
        RPTP(DOTP)
        float a1_0 = acc1_0v[0] + acc1_0v[1];
        float a1_1 = acc1_1v[0] + acc1_1v[1];
        float a2_0 = __builtin_fmaf(accl_0v[0] + accl_0v[1], SCLF, acc2_0);
        float a2_1 = __builtin_fmaf(accl_1v[0] + accl_1v[1], SCLF, acc2_1);
        QUADSUM(a1_0) QUADSUM(a1_1) QUADSUM(a2_0) QUADSUM(a2_1)
        float s1 = (q & 1) ? a1_1 : a1_0;
        float s2 = (q & 1) ? a2_1 : a2_0;
        zmine = zmine + ftanh(s1 + x1m) + ftanh(s2 + x2m) * dxt;
        if (q < 2) *(float*)(RsB + (rbase ^ 1024) + myrow * 4) = zmine;
        __syncthreads();
        rbase ^= 1024;
    }

    if (q < 2) Zlin[myrow] = zmine;
    __syncthreads();

    if (tid < 32) {
        float a = b2h[tid];
        const float* wrow = W2h + tid * RD;
        for (int k = 0; k < RD; ++k) a = __builtin_fmaf(wrow[k], Zlin[k], a);
        hh[tid] = ftanh(a);
    }
    __syncthreads();
    if (tid < RD - 30) {
        float a = b2o[tid];
        const float* wrow = W2o + tid * 32;
        for (int k = 0; k < 32; ++k) a = __builtin_fmaf(wrow[k], hh[k], a);
        rsig_out[tid] = a;
    }
}

extern "C" void kernel_launch(void* const* d_in, const int* in_sizes, int n_in,
                              void* d_out, int out_size, void* d_ws, size_t ws_size,
                              hipStream_t stream) {
    const float* x_past  = (const float*)d_in[2];
    const float* V_noise = (const float*)d_in[3];
    const float* inc     = (const float*)d_in[4];
    const float* W1h     = (const float*)d_in[5];
    const float* b1h     = (const float*)d_in[6];
    const float* W1o     = (const float*)d_in[7];
    const float* b1o     = (const float*)d_in[8];
    const float* W2h     = (const float*)d_in[9];
    const float* b2h     = (const float*)d_in[10];
    const float* W2o     = (const float*)d_in[11];
    const float* b2o     = (const float*)d_in[12];
    const float* rho1    = (const float*)d_in[13];
    const float* rho2    = (const float*)d_in[14];
    const float* rho3    = (const float*)d_in[15];
    const float* rho4    = (const float*)d_in[16];
    const float* B1      = (const float*)d_in[17];
    const float* B2      = (const float*)d_in[18];
    const float* lam1    = (const float*)d_in[19];
    const float* lam2    = (const float*)d_in[20];
    const float* A1      = (const float*)d_in[21];
    const float* A2      = (const float*)d_in[22];
    const float* xi1     = (const float*)d_in[23];
    const float* xi2     = (const float*)d_in[24];
    const float* Wr      = (const float*)d_in[25];
    const float* br      = (const float*)d_in[26];

    float* rsig_ws = (float*)d_ws;   // 226 floats

    rsig_kernel<<<1, 512, 0, stream>>>(x_past, A1, A2, xi1, xi2,
                                       W2h, b2h, W2o, b2o, rsig_ws);

    sde_main_kernel<<<256, 512, 0, stream>>>(inc, V_noise, W1h, b1h, W1o, b1o,
                                             rho1, rho2, rho3, rho4,
                                             B1, B2, lam1, lam2, Wr, br,
                                             rsig_ws, (float*)d_out);
}